// Round 8
// baseline (385.196 us; speedup 1.0000x reference)
//
#include <hip/hip_runtime.h>
#include <cstddef>
#include <cstdint>

// Problem constants
#define HH 8
#define FF 512
#define CC 256
#define SS 512
#define BB 64
#define SB (SS*BB)   // 32768

typedef __attribute__((ext_vector_type(4))) float f32x4;
typedef __attribute__((ext_vector_type(8))) short bf16x8;

typedef __attribute__((address_space(1))) unsigned int gu32_t;
typedef __attribute__((address_space(3))) unsigned int lu32_t;

// Async global->LDS, 16B per lane. LDS dest = wave-uniform base + lane*16.
__device__ __forceinline__ void gld16(const void* gp, void* lp) {
    __builtin_amdgcn_global_load_lds((gu32_t*)gp, (lu32_t*)lp, 16, 0, 0);
}

__device__ __forceinline__ float fast_tanh(float x) {
    float e = __expf(2.0f * x);
    return 1.0f - 2.0f / (e + 1.0f);
}
__device__ __forceinline__ float relu_f(float x) { return fmaxf(x, 0.0f); }

__device__ __forceinline__ unsigned short f2bf(float x) {
    unsigned u = __float_as_uint(x);
    unsigned r = u + 0x7FFFu + ((u >> 16) & 1u);
    return (unsigned short)(r >> 16);
}
__device__ __forceinline__ float bf2f(unsigned short h) {
    return __uint_as_float(((unsigned)h) << 16);
}

// ---------------------------------------------------------------------------
// Swizzled operand-tile format ("image" format), shared by all MFMA GEMMs:
//   For a logical matrix of rows n (output dim) x k (reduce dim), split fp32
//   into bf16 hi/lo. Layout: [kt = k/32][n][p][8 bf16], where for k-granule
//   g = (k>>3)&3 and h in {hi=0, lo=1}: q = 2g+h, p = q ^ (n&7).
//   Row block = 128 B. This is EXACTLY the LDS image each k-step wants, so
//   staging is linear global_load_lds; ds_read uses p = (2*quad+h) ^ (cb&7).
// ---------------------------------------------------------------------------

// ---------------------------------------------------------------------------
// D2CONV: d2 (fp32 [SB][FF]) -> d2s image (16 kt planes). Memory-bound
// prepass hoisting k1's in-loop fp32->hi/lo conversion out of the hot loop.
// Each thread: one row, 16 consecutive k (2 granules x hi/lo).
// ---------------------------------------------------------------------------
__global__ __launch_bounds__(256) void d2_conv(
    const float* __restrict__ d2, unsigned short* __restrict__ d2s)
{
    const int tid = threadIdx.x;
    const int bid = blockIdx.x;
    const int row  = bid * 8 + (tid >> 5);     // 8 rows per block
    const int kseg = (tid & 31) * 16;          // 16 k per thread
    const float* s = d2 + (size_t)row * FF + kseg;
    float v[16];
    *(float4*)&v[0]  = *(const float4*)(s);
    *(float4*)&v[4]  = *(const float4*)(s + 4);
    *(float4*)&v[8]  = *(const float4*)(s + 8);
    *(float4*)&v[12] = *(const float4*)(s + 12);
    bf16x8 vh0, vh1, vl0, vl1;
    #pragma unroll
    for (int j = 0; j < 8; ++j) {
        unsigned short h = f2bf(v[j]);
        vh0[j] = (short)h; vl0[j] = (short)f2bf(v[j] - bf2f(h));
        unsigned short h2 = f2bf(v[j+8]);
        vh1[j] = (short)h2; vl1[j] = (short)f2bf(v[j+8] - bf2f(h2));
    }
    const int rx = row & 7;
    const int kt = kseg >> 5;
    const int g0 = (kseg >> 3) & 3;            // 0 or 2
    unsigned short* dst = d2s + ((size_t)kt * SB + row) * 64;
    *(bf16x8*)&dst[((2*g0 + 0) ^ rx) * 8] = vh0;
    *(bf16x8*)&dst[((2*g0 + 1) ^ rx) * 8] = vl0;
    *(bf16x8*)&dst[((2*g0 + 2) ^ rx) * 8] = vh1;
    *(bf16x8*)&dst[((2*g0 + 3) ^ rx) * 8] = vl1;
}

// ---------------------------------------------------------------------------
// PREP: bid<192: transpose+split of w1/wv (-> 16 kt planes) and W[h] rows
//       0..C-1 (-> 8 kt planes), emitted in image format.
//       bid 192..195: d4 = relu(d1@w1+b1) (fp32, 64x64 tile each).
// ---------------------------------------------------------------------------
__global__ __launch_bounds__(256) void p_prep(
    const float* __restrict__ w1, const float* __restrict__ wv,
    const float* __restrict__ W, const float* __restrict__ d1,
    const float* __restrict__ b1,
    unsigned short* __restrict__ w1ts, unsigned short* __restrict__ wvts,
    unsigned short* __restrict__ Wts, float* __restrict__ d4)
{
    __shared__ float T[64][65];
    __shared__ float As[16][68];
    __shared__ float Bs[16][68];
    const int tid = threadIdx.x;
    const int bid = blockIdx.x;
    if (bid < 192) {
        const float* src;
        unsigned short* dst;
        int kt64, nt;
        if (bid < 64) {
            int m = bid >> 5;            // 0: w1, 1: wv
            int t = bid & 31;
            kt64 = t >> 2; nt = t & 3;
            src = m ? wv : w1;
            dst = m ? wvts : w1ts;
        } else {
            int t = bid - 64;
            int h = t >> 4; int tt = t & 15;
            kt64 = tt >> 2; nt = tt & 3;
            src = W + (size_t)h * 2 * CC * CC;
            dst = Wts + (size_t)h * 8 * CC * 64;
        }
        const int k0 = kt64 * 64, n0 = nt * 64;
        #pragma unroll
        for (int jj = 0; jj < 4; ++jj) {
            int i = (tid >> 4) + jj * 16;
            int j = (tid & 15) * 4;
            float4 v = *(const float4*)(src + (size_t)(k0 + i) * CC + n0 + j);
            T[i][j] = v.x; T[i][j+1] = v.y; T[i][j+2] = v.z; T[i][j+3] = v.w;
        }
        __syncthreads();
        // write: each thread owns one n, 16 consecutive k (2 granules)
        {
            const int n_local = tid & 63;
            const int kg = (tid >> 6) * 16;
            const int n_abs = n0 + n_local;
            const int sxn = n_abs & 7;
            #pragma unroll
            for (int j = 0; j < 2; ++j) {
                const int kbase = kg + j * 8;
                const int k_abs = k0 + kbase;
                const int kt = k_abs >> 5;
                const int g = (k_abs >> 3) & 3;
                bf16x8 hv8, lv8;
                #pragma unroll
                for (int q = 0; q < 8; ++q) {
                    float x = T[kbase + q][n_local];
                    unsigned short hx = f2bf(x);
                    hv8[q] = (short)hx;
                    lv8[q] = (short)f2bf(x - bf2f(hx));
                }
                size_t rowo = ((size_t)kt * CC + n_abs) * 64;
                *(bf16x8*)(dst + rowo + (size_t)((2*g + 0) ^ sxn) * 8) = hv8;
                *(bf16x8*)(dst + rowo + (size_t)((2*g + 1) ^ sxn) * 8) = lv8;
            }
        }
    } else {
        // d4 tile: 64 rows x 64 cols (n0), fp32 vector GEMM
        const int n0 = (bid - 192) * 64;
        const int tx = tid & 15, ty = tid >> 4;
        const int lm = tid >> 2, lk4 = (tid & 3) * 4;
        const int bk = tid >> 4, bn4 = (tid & 15) * 4;
        float acc[4][4] = {};
        for (int k0 = 0; k0 < FF; k0 += 16) {
            float4 a = *(const float4*)(d1 + (size_t)lm * FF + k0 + lk4);
            As[lk4+0][lm] = a.x; As[lk4+1][lm] = a.y;
            As[lk4+2][lm] = a.z; As[lk4+3][lm] = a.w;
            *(float4*)&Bs[bk][bn4] = *(const float4*)(w1 + (size_t)(k0+bk)*CC + n0 + bn4);
            __syncthreads();
            #pragma unroll
            for (int kk = 0; kk < 16; ++kk) {
                float4 a4 = *(const float4*)&As[kk][ty*4];
                float4 b4 = *(const float4*)&Bs[kk][tx*4];
                float av[4] = {a4.x, a4.y, a4.z, a4.w};
                float bv[4] = {b4.x, b4.y, b4.z, b4.w};
                #pragma unroll
                for (int i = 0; i < 4; ++i)
                    #pragma unroll
                    for (int j = 0; j < 4; ++j)
                        acc[i][j] = fmaf(av[i], bv[j], acc[i][j]);
            }
            __syncthreads();
        }
        #pragma unroll
        for (int i = 0; i < 4; ++i) {
            int row = ty*4 + i;
            #pragma unroll
            for (int j = 0; j < 4; ++j)
                d4[(size_t)row*CC + n0 + tx*4 + j] = relu_f(acc[i][j] + b1[n0 + tx*4 + j]);
        }
    }
}

// ---------------------------------------------------------------------------
// K1 (v2): bid<512: 128-row x 256-col MFMA GEMM over d2s image (K=512),
//   path = bid>>8: 0 -> d3 (image format) = relu(.@w1+b1), 1 -> tv = tanh(.@wv).
//   A AND B now staged via pure global_load_lds from pre-swizzled images
//   (conversion hoisted to d2_conv) — same verified structure as k3.
// bid>=512: e4[h, ntile] fp32 GEMM (d4 @ W[h][C:]), LDS aliased onto buffers.
// ---------------------------------------------------------------------------
__global__ __launch_bounds__(256, 2) void k1_main(
    const unsigned short* __restrict__ d2s,
    const unsigned short* __restrict__ w1ts, const unsigned short* __restrict__ wvts,
    const float* __restrict__ b1,
    const float* __restrict__ d4, const float* __restrict__ W,
    unsigned short* __restrict__ d3s, unsigned short* __restrict__ tv,
    float* __restrict__ e4)
{
    __shared__ __align__(16) unsigned short Abuf[128 * 64];   // 16 KB
    __shared__ __align__(16) unsigned short Bbuf[256 * 64];   // 32 KB

    const int tid = threadIdx.x;
    const int bid = blockIdx.x;

    if (bid >= 512) {
        // ---- e4 path (fp32 vector, tiny). Alias LDS onto buffers. ----
        float (*As)[68] = (float(*)[68])&Abuf[0];
        float (*Bs)[68] = (float(*)[68])&Bbuf[0];
        const int idx = bid - 512;
        const int n0 = (idx & 3) * 64;
        const int h  = idx >> 2;
        const float* Wh = W + ((size_t)h * 2 * CC + CC) * CC;
        const int tx = tid & 15, ty = tid >> 4;
        const int lm = tid >> 2, lk4 = (tid & 3) * 4;
        const int bk = tid >> 4, bn4 = (tid & 15) * 4;
        float acc[4][4] = {};
        for (int k0 = 0; k0 < CC; k0 += 16) {
            float4 a = *(const float4*)(d4 + (size_t)lm * CC + k0 + lk4);
            As[lk4+0][lm] = a.x; As[lk4+1][lm] = a.y;
            As[lk4+2][lm] = a.z; As[lk4+3][lm] = a.w;
            *(float4*)&Bs[bk][bn4] = *(const float4*)(Wh + (size_t)(k0+bk)*CC + n0 + bn4);
            __syncthreads();
            #pragma unroll
            for (int kk = 0; kk < 16; ++kk) {
                float4 a4 = *(const float4*)&As[kk][ty*4];
                float4 b4 = *(const float4*)&Bs[kk][tx*4];
                float av[4] = {a4.x, a4.y, a4.z, a4.w};
                float bv[4] = {b4.x, b4.y, b4.z, b4.w};
                #pragma unroll
                for (int i = 0; i < 4; ++i)
                    #pragma unroll
                    for (int j = 0; j < 4; ++j)
                        acc[i][j] = fmaf(av[i], bv[j], acc[i][j]);
            }
            __syncthreads();
        }
        #pragma unroll
        for (int i = 0; i < 4; ++i) {
            int b = ty*4 + i;
            #pragma unroll
            for (int j = 0; j < 4; ++j)
                e4[((size_t)h*BB + b)*CC + n0 + tx*4 + j] = acc[i][j];
        }
        return;
    }

    // ---- main GEMM path ----
    const int path = bid >> 8;              // 0: w1->d3, 1: wv->tv
    const int r0 = (bid & 255) * 128;
    const int lane = tid & 63, w = tid >> 6;
    const int rowgrp = w & 1, colgrp = w >> 1;
    const int cb = lane & 15, quad = lane >> 4;
    const unsigned short* BT = path ? wvts : w1ts;

    f32x4 acc[4][8];
    f32x4 zero = {0.0f, 0.0f, 0.0f, 0.0f};
    #pragma unroll
    for (int rt = 0; rt < 4; ++rt)
        #pragma unroll
        for (int ct = 0; ct < 8; ++ct) acc[rt][ct] = zero;

    const int phi = (2 * quad) ^ (cb & 7);           // read-side swizzle (hi)

    for (int k0 = 0; k0 < FF; k0 += 32) {
        const int kt = k0 >> 5;
        // stage A: 128 rows x 32 k image (16 KB), 4 x 1KB per wave
        {
            const unsigned short* Asrc = d2s + ((size_t)kt * SB + r0) * 64;
            #pragma unroll
            for (int i = 0; i < 4; ++i) {
                int chunk = i * 4 + w;
                gld16(Asrc + (size_t)chunk * 512 + lane * 8, &Abuf[chunk * 512]);
            }
        }
        // stage B: 256 n x 32 k image, 32 KB via global_load_lds (8 x 1KB/wave)
        {
            const unsigned short* Bsrc = BT + (size_t)kt * (CC * 64);
            #pragma unroll
            for (int i = 0; i < 8; ++i) {
                int chunk = i * 4 + w;
                gld16(Bsrc + (size_t)chunk * 512 + lane * 8, &Bbuf[chunk * 512]);
            }
        }
        __syncthreads();
        bf16x8 ahf[4], alf[4];
        #pragma unroll
        for (int rt = 0; rt < 4; ++rt) {
            const unsigned short* Arow = &Abuf[(rowgrp*64 + rt*16 + cb) * 64];
            ahf[rt] = *(const bf16x8*)&Arow[phi * 8];
            alf[rt] = *(const bf16x8*)&Arow[(phi ^ 1) * 8];
        }
        #pragma unroll
        for (int ct = 0; ct < 8; ++ct) {
            const unsigned short* Brow = &Bbuf[(colgrp*128 + ct*16 + cb) * 64];
            bf16x8 bh = *(const bf16x8*)&Brow[phi * 8];
            bf16x8 bl = *(const bf16x8*)&Brow[(phi ^ 1) * 8];
            #pragma unroll
            for (int rt = 0; rt < 4; ++rt) {
                acc[rt][ct] = __builtin_amdgcn_mfma_f32_16x16x32_bf16(ahf[rt], bh, acc[rt][ct], 0, 0, 0);
                acc[rt][ct] = __builtin_amdgcn_mfma_f32_16x16x32_bf16(ahf[rt], bl, acc[rt][ct], 0, 0, 0);
                acc[rt][ct] = __builtin_amdgcn_mfma_f32_16x16x32_bf16(alf[rt], bh, acc[rt][ct], 0, 0, 0);
            }
        }
        __syncthreads();
    }
    // epilogue. C layout: col = ct*16+cb (+colgrp*128), row = rt*16+quad*4+r (+rowgrp*64)
    if (path == 0) {
        float bias[8];
        #pragma unroll
        for (int ct = 0; ct < 8; ++ct) bias[ct] = b1[colgrp*128 + ct*16 + cb];
        #pragma unroll
        for (int rt = 0; rt < 4; ++rt) {
            #pragma unroll
            for (int r = 0; r < 4; ++r) {
                int gr = r0 + rowgrp*64 + rt*16 + quad*4 + r;
                int sxr = gr & 7;
                #pragma unroll
                for (int ct = 0; ct < 8; ++ct) {
                    int c = colgrp*128 + ct*16 + cb;
                    float val = relu_f(acc[rt][ct][r] + bias[ct]);
                    unsigned short hx = f2bf(val);
                    unsigned short lx = f2bf(val - bf2f(hx));
                    int kt = c >> 5;
                    int g = (c >> 3) & 3;
                    size_t rowo = ((size_t)kt * SB + gr) * 64;
                    d3s[rowo + (size_t)((2*g + 0) ^ sxr) * 8 + (c & 7)] = hx;
                    d3s[rowo + (size_t)((2*g + 1) ^ sxr) * 8 + (c & 7)] = lx;
                }
            }
        }
    } else {
        #pragma unroll
        for (int rt = 0; rt < 4; ++rt) {
            #pragma unroll
            for (int r = 0; r < 4; ++r) {
                int gr = r0 + rowgrp*64 + rt*16 + quad*4 + r;
                int s = gr >> 6, b = gr & 63;
                #pragma unroll
                for (int ct = 0; ct < 8; ++ct) {
                    int c = colgrp*128 + ct*16 + cb;
                    tv[((size_t)b * SS + s) * CC + c] = f2bf(fast_tanh(acc[rt][ct][r]));
                }
            }
        }
    }
}

// ---------------------------------------------------------------------------
// K3 (= R7 verified: R1 structure + XCD-grouping decode + launch_bounds(256,2)):
// atts[h,b,s] = sum_c P[h,c]*tanh((d3@Wt[h])[row,c] + e4[h,b,c]).
// Block: 128 rows x 256 cols, one head; A+B via global_load_lds from
// pre-swizzled images; LDS 48 KB (red aliased onto Abuf). VGPR 108,
// 2 blocks/CU, FETCH ~28 MB (verified R7: 124 us).
// ---------------------------------------------------------------------------
__global__ __launch_bounds__(256, 2) void k3_atts(
    const unsigned short* __restrict__ d3s, const unsigned short* __restrict__ Wts,
    const float* __restrict__ e4, const float* __restrict__ P,
    float* __restrict__ atts)
{
    __shared__ __align__(16) unsigned short Abuf[128 * 64];   // 16 KB
    __shared__ __align__(16) unsigned short Bbuf[256 * 64];   // 32 KB
    float (*red)[128] = (float(*)[128])&Abuf[0];  // aliased; live only post-K-loop

    const int tid = threadIdx.x;
    const int lane = tid & 63, w = tid >> 6;
    const int bid = blockIdx.x;
    // bijective XCD-grouping decode (assumes XCD = bid % 8 round-robin)
    const int cxcd = bid & 7;
    const int jj   = bid >> 3;
    const int h    = jj & 7;
    const int xb   = (jj >> 3) * 8 + cxcd;     // row-block 0..255
    const int r0   = xb * 128;
    const int rowgrp = w & 1, colgrp = w >> 1;
    const int cb = lane & 15, quad = lane >> 4;
    const int phi = (2 * quad) ^ (cb & 7);

    const unsigned short* Wh = Wts + (size_t)h * (8 * CC * 64);

    f32x4 acc[4][8];
    f32x4 zero = {0.0f, 0.0f, 0.0f, 0.0f};
    #pragma unroll
    for (int rt = 0; rt < 4; ++rt)
        #pragma unroll
        for (int ct = 0; ct < 8; ++ct) acc[rt][ct] = zero;

    for (int kt = 0; kt < 8; ++kt) {
        // stage A: 128 rows x 32 k image (16 KB), 4 x 1KB per wave
        {
            const unsigned short* Asrc = d3s + ((size_t)kt * SB + r0) * 64;
            #pragma unroll
            for (int i = 0; i < 4; ++i) {
                int chunk = i * 4 + w;
                gld16(Asrc + (size_t)chunk * 512 + lane * 8, &Abuf[chunk * 512]);
            }
        }
        // stage B: 256 n x 32 k image (32 KB), 8 x 1KB per wave
        {
            const unsigned short* Bsrc = Wh + (size_t)kt * (CC * 64);
            #pragma unroll
            for (int i = 0; i < 8; ++i) {
                int chunk = i * 4 + w;
                gld16(Bsrc + (size_t)chunk * 512 + lane * 8, &Bbuf[chunk * 512]);
            }
        }
        __syncthreads();   // drains vmcnt -> LDS image ready
        bf16x8 ahf[4], alf[4];
        #pragma unroll
        for (int rt = 0; rt < 4; ++rt) {
            const unsigned short* Arow = &Abuf[(rowgrp*64 + rt*16 + cb) * 64];
            ahf[rt] = *(const bf16x8*)&Arow[phi * 8];
            alf[rt] = *(const bf16x8*)&Arow[(phi ^ 1) * 8];
        }
        #pragma unroll
        for (int ct = 0; ct < 8; ++ct) {
            const unsigned short* Brow = &Bbuf[(colgrp*128 + ct*16 + cb) * 64];
            bf16x8 bh = *(const bf16x8*)&Brow[phi * 8];
            bf16x8 bl = *(const bf16x8*)&Brow[(phi ^ 1) * 8];
            #pragma unroll
            for (int rt = 0; rt < 4; ++rt) {
                acc[rt][ct] = __builtin_amdgcn_mfma_f32_16x16x32_bf16(ahf[rt], bh, acc[rt][ct], 0, 0, 0);
                acc[rt][ct] = __builtin_amdgcn_mfma_f32_16x16x32_bf16(ahf[rt], bl, acc[rt][ct], 0, 0, 0);
                acc[rt][ct] = __builtin_amdgcn_mfma_f32_16x16x32_bf16(alf[rt], bh, acc[rt][ct], 0, 0, 0);
            }
        }
        __syncthreads();
    }
    // epilogue: tanh + P-dot over this wave's 128 cols, then reduce.
    // (red aliases Abuf; all Abuf reads completed before the last barrier.)
    float Pv[8];
    #pragma unroll
    for (int ct = 0; ct < 8; ++ct) Pv[ct] = P[(size_t)h * CC + colgrp*128 + ct*16 + cb];
    #pragma unroll
    for (int rt = 0; rt < 4; ++rt) {
        #pragma unroll
        for (int r = 0; r < 4; ++r) {
            int b = rt*16 + quad*4 + r;     // batch index (mod 64)
            const float* e4p = e4 + ((size_t)h * BB + b) * CC + colgrp*128 + cb;
            float part = 0.0f;
            #pragma unroll
            for (int ct = 0; ct < 8; ++ct) {
                float u = acc[rt][ct][r] + e4p[ct*16];
                part = fmaf(Pv[ct], fast_tanh(u), part);
            }
            part += __shfl_xor(part, 1); part += __shfl_xor(part, 2);
            part += __shfl_xor(part, 4); part += __shfl_xor(part, 8);
            if (cb == 0) red[colgrp][rowgrp*64 + b] = part;
        }
    }
    __syncthreads();
    if (tid < 128) {
        float v = red[0][tid] + red[1][tid];
        int gr = r0 + tid;
        int s = gr >> 6, b = gr & 63;
        atts[((size_t)h * BB + b) * SS + s] = v;
    }
}

// ---------------------------------------------------------------------------
// K456: per b: softmax over s (8 heads) + vs = scores.tv + out = relu(vs@wcc+bcc)
// ---------------------------------------------------------------------------
__global__ __launch_bounds__(256) void k456_out(
    const float* __restrict__ atts, const unsigned short* __restrict__ tv,
    const float* __restrict__ wcc, const float* __restrict__ bcc,
    float* __restrict__ out)
{
    __shared__ float sc[HH][SS];       // 16 KB
    __shared__ float red[4][2048];     // 32 KB
    const int b = blockIdx.x;
    const int tid = threadIdx.x;
    const int lane = tid & 63, w = tid >> 6;

    for (int i = tid; i < HH*SS; i += 256) {
        int h = i >> 9, s = i & 511;
        sc[h][s] = atts[((size_t)h*BB + b)*SS + s];
    }
    __syncthreads();
    // softmax: wave w handles heads 2w, 2w+1
    #pragma unroll
    for (int t = 0; t < 2; ++t) {
        int hh = w*2 + t;
        float x[8];
        #pragma unroll
        for (int j = 0; j < 8; ++j) x[j] = sc[hh][j*64 + lane];
        float m = x[0];
        #pragma unroll
        for (int j = 1; j < 8; ++j) m = fmaxf(m, x[j]);
        #pragma unroll
        for (int d = 1; d < 64; d <<= 1) m = fmaxf(m, __shfl_xor(m, d));
        float sum = 0.0f;
        #pragma unroll
        for (int j = 0; j < 8; ++j) { x[j] = __expf(x[j] - m); sum += x[j]; }
        #pragma unroll
        for (int d = 1; d < 64; d <<= 1) sum += __shfl_xor(sum, d);
        float inv = 1.0f / sum;
        #pragma unroll
        for (int j = 0; j < 8; ++j) sc[hh][j*64 + lane] = x[j] * inv;
    }
    __syncthreads();
    // vs: stripe = s-range of 128, each lane owns 4 c
    {
        const int cl = tid & 63, stripe = tid >> 6;
        const int c0 = cl * 4;
        const unsigned short* tvb = tv + ((size_t)b * SS + stripe * 128) * CC + c0;
        float acc[HH][4] = {};
        for (int si = 0; si < 128; ++si) {
            uint2 u = *(const uint2*)(tvb + (size_t)si * CC);
            float x0 = bf2f((unsigned short)(u.x));
            float x1 = bf2f((unsigned short)(u.x >> 16));
            float x2 = bf2f((unsigned short)(u.y));
            float x3 = bf2f((unsigned short)(u.y >> 16));
            int s = stripe * 128 + si;
            #pragma unroll
            for (int h = 0; h < HH; ++h) {
                float wgt = sc[h][s];
                acc[h][0] = fmaf(wgt, x0, acc[h][0]);
                acc[h][1] = fmaf(wgt, x1, acc[h][1]);
                acc[h][2] = fmaf(wgt, x2, acc[h][2]);
                acc[h][3] = fmaf(wgt, x3, acc[h][3]);
            }
        }
        #pragma unroll
        for (int h = 0; h < HH; ++h)
            #pragma unroll
            for (int j = 0; j < 4; ++j)
                red[stripe][h*256 + c0 + j] = acc[h][j];
    }
    __syncthreads();
    for (int i = tid; i < 2048; i += 256)
        red[0][i] = red[0][i] + red[1][i] + red[2][i] + red[3][i];
    __syncthreads();
    // out: 2 threads per output column
    {
        const int n = tid & 127, half = tid >> 7;
        float o = 0.0f;
        const int kbase = half * 1024;
        for (int k = 0; k < 1024; ++k)
            o = fmaf(red[0][kbase + k], wcc[(size_t)(kbase + k) * 128 + n], o);
        float* r2 = &sc[0][0];
        r2[half * 128 + n] = o;
    }
    __syncthreads();
    if (tid < 128)
        out[(size_t)b * 128 + tid] = relu_f(sc[0][tid] + sc[0][128 + tid] + bcc[tid]);
}

// ---------------------------------------------------------------------------
extern "C" void kernel_launch(void* const* d_in, const int* in_sizes, int n_in,
                              void* d_out, int out_size, void* d_ws, size_t ws_size,
                              hipStream_t stream)
{
    (void)in_sizes; (void)n_in; (void)out_size; (void)ws_size;
    const float* d1  = (const float*)d_in[0];
    const float* d2  = (const float*)d_in[1];
    const float* w1  = (const float*)d_in[2];
    const float* b1  = (const float*)d_in[3];
    const float* W   = (const float*)d_in[4];
    const float* P   = (const float*)d_in[5];
    const float* wv  = (const float*)d_in[6];
    const float* wcc = (const float*)d_in[7];
    const float* bcc = (const float*)d_in[8];
    float* out = (float*)d_out;

    char* p = (char*)d_ws;
    unsigned short* d3s  = (unsigned short*)p; p += (size_t)8 * SB * 64 * 2;       // 33.55 MB
    unsigned short* tv   = (unsigned short*)p; p += (size_t)SB * CC * 2;           // 16.78 MB
    unsigned short* w1ts = (unsigned short*)p; p += (size_t)16 * CC * 64 * 2;      // 512 KB
    unsigned short* wvts = (unsigned short*)p; p += (size_t)16 * CC * 64 * 2;      // 512 KB
    unsigned short* Wts  = (unsigned short*)p; p += (size_t)HH * 8 * CC * 64 * 2;  // 2 MB
    unsigned short* d2s  = (unsigned short*)p; p += (size_t)16 * SB * 64 * 2;      // 67.1 MB
    float* d4   = (float*)p;  p += (size_t)BB * CC * 4;
    float* e4   = (float*)p;  p += (size_t)HH * BB * CC * 4;
    float* atts = (float*)p;  p += (size_t)HH * BB * SS * 4;

    d2_conv  <<<dim3(4096),      256, 0, stream>>>(d2, d2s);
    p_prep   <<<dim3(196),       256, 0, stream>>>(w1, wv, W, d1, b1,
                  w1ts, wvts, Wts, d4);
    k1_main  <<<dim3(544),       256, 0, stream>>>(d2s, w1ts, wvts, b1, d4, W,
                  d3s, tv, e4);
    k3_atts  <<<dim3(2048),      256, 0, stream>>>(d3s, Wts, e4, P, atts);
    k456_out <<<dim3(BB),        256, 0, stream>>>(atts, tv, wcc, bcc, out);
}

// Round 9
// 354.286 us; speedup vs baseline: 1.0872x; 1.0872x over previous
//
#include <hip/hip_runtime.h>
#include <cstddef>
#include <cstdint>

// Problem constants
#define HH 8
#define FF 512
#define CC 256
#define SS 512
#define BB 64
#define SB (SS*BB)   // 32768

typedef __attribute__((ext_vector_type(4))) float f32x4;
typedef __attribute__((ext_vector_type(8))) short bf16x8;

typedef __attribute__((address_space(1))) unsigned int gu32_t;
typedef __attribute__((address_space(3))) unsigned int lu32_t;

// Async global->LDS, 16B per lane. LDS dest = wave-uniform base + lane*16.
__device__ __forceinline__ void gld16(const void* gp, void* lp) {
    __builtin_amdgcn_global_load_lds((gu32_t*)gp, (lu32_t*)lp, 16, 0, 0);
}

__device__ __forceinline__ float fast_tanh(float x) {
    float e = __expf(2.0f * x);
    return 1.0f - 2.0f / (e + 1.0f);
}
__device__ __forceinline__ float relu_f(float x) { return fmaxf(x, 0.0f); }

__device__ __forceinline__ unsigned short f2bf(float x) {
    unsigned u = __float_as_uint(x);
    unsigned r = u + 0x7FFFu + ((u >> 16) & 1u);
    return (unsigned short)(r >> 16);
}
__device__ __forceinline__ float bf2f(unsigned short h) {
    return __uint_as_float(((unsigned)h) << 16);
}

// ---------------------------------------------------------------------------
// Swizzled operand-tile format ("image" format), shared by all MFMA GEMMs:
//   For a logical matrix of rows n (output dim) x k (reduce dim), split fp32
//   into bf16 hi/lo. Layout: [kt = k/32][n][p][8 bf16], where for k-granule
//   g = (k>>3)&3 and h in {hi=0, lo=1}: q = 2g+h, p = q ^ (n&7).
//   Row block = 128 B. This is EXACTLY the LDS image each k-step wants, so
//   staging is linear global_load_lds; ds_read uses p = (2*quad+h) ^ (cb&7).
// ---------------------------------------------------------------------------

// ---------------------------------------------------------------------------
// PREP: bid<192: transpose+split of w1/wv (-> 16 kt planes) and W[h] rows
//       0..C-1 (-> 8 kt planes), emitted in image format.
//       bid 192..195: d4 = relu(d1@w1+b1) (fp32, 64x64 tile each).
// ---------------------------------------------------------------------------
__global__ __launch_bounds__(256) void p_prep(
    const float* __restrict__ w1, const float* __restrict__ wv,
    const float* __restrict__ W, const float* __restrict__ d1,
    const float* __restrict__ b1,
    unsigned short* __restrict__ w1ts, unsigned short* __restrict__ wvts,
    unsigned short* __restrict__ Wts, float* __restrict__ d4)
{
    __shared__ float T[64][65];
    __shared__ float As[16][68];
    __shared__ float Bs[16][68];
    const int tid = threadIdx.x;
    const int bid = blockIdx.x;
    if (bid < 192) {
        const float* src;
        unsigned short* dst;
        int kt64, nt;
        if (bid < 64) {
            int m = bid >> 5;            // 0: w1, 1: wv
            int t = bid & 31;
            kt64 = t >> 2; nt = t & 3;
            src = m ? wv : w1;
            dst = m ? wvts : w1ts;
        } else {
            int t = bid - 64;
            int h = t >> 4; int tt = t & 15;
            kt64 = tt >> 2; nt = tt & 3;
            src = W + (size_t)h * 2 * CC * CC;
            dst = Wts + (size_t)h * 8 * CC * 64;
        }
        const int k0 = kt64 * 64, n0 = nt * 64;
        #pragma unroll
        for (int jj = 0; jj < 4; ++jj) {
            int i = (tid >> 4) + jj * 16;
            int j = (tid & 15) * 4;
            float4 v = *(const float4*)(src + (size_t)(k0 + i) * CC + n0 + j);
            T[i][j] = v.x; T[i][j+1] = v.y; T[i][j+2] = v.z; T[i][j+3] = v.w;
        }
        __syncthreads();
        // write: each thread owns one n, 16 consecutive k (2 granules)
        {
            const int n_local = tid & 63;
            const int kg = (tid >> 6) * 16;
            const int n_abs = n0 + n_local;
            const int sxn = n_abs & 7;
            #pragma unroll
            for (int j = 0; j < 2; ++j) {
                const int kbase = kg + j * 8;
                const int k_abs = k0 + kbase;
                const int kt = k_abs >> 5;
                const int g = (k_abs >> 3) & 3;
                bf16x8 hv8, lv8;
                #pragma unroll
                for (int q = 0; q < 8; ++q) {
                    float x = T[kbase + q][n_local];
                    unsigned short hx = f2bf(x);
                    hv8[q] = (short)hx;
                    lv8[q] = (short)f2bf(x - bf2f(hx));
                }
                size_t rowo = ((size_t)kt * CC + n_abs) * 64;
                *(bf16x8*)(dst + rowo + (size_t)((2*g + 0) ^ sxn) * 8) = hv8;
                *(bf16x8*)(dst + rowo + (size_t)((2*g + 1) ^ sxn) * 8) = lv8;
            }
        }
    } else {
        // d4 tile: 64 rows x 64 cols (n0), fp32 vector GEMM
        const int n0 = (bid - 192) * 64;
        const int tx = tid & 15, ty = tid >> 4;
        const int lm = tid >> 2, lk4 = (tid & 3) * 4;
        const int bk = tid >> 4, bn4 = (tid & 15) * 4;
        float acc[4][4] = {};
        for (int k0 = 0; k0 < FF; k0 += 16) {
            float4 a = *(const float4*)(d1 + (size_t)lm * FF + k0 + lk4);
            As[lk4+0][lm] = a.x; As[lk4+1][lm] = a.y;
            As[lk4+2][lm] = a.z; As[lk4+3][lm] = a.w;
            *(float4*)&Bs[bk][bn4] = *(const float4*)(w1 + (size_t)(k0+bk)*CC + n0 + bn4);
            __syncthreads();
            #pragma unroll
            for (int kk = 0; kk < 16; ++kk) {
                float4 a4 = *(const float4*)&As[kk][ty*4];
                float4 b4 = *(const float4*)&Bs[kk][tx*4];
                float av[4] = {a4.x, a4.y, a4.z, a4.w};
                float bv[4] = {b4.x, b4.y, b4.z, b4.w};
                #pragma unroll
                for (int i = 0; i < 4; ++i)
                    #pragma unroll
                    for (int j = 0; j < 4; ++j)
                        acc[i][j] = fmaf(av[i], bv[j], acc[i][j]);
            }
            __syncthreads();
        }
        #pragma unroll
        for (int i = 0; i < 4; ++i) {
            int row = ty*4 + i;
            #pragma unroll
            for (int j = 0; j < 4; ++j)
                d4[(size_t)row*CC + n0 + tx*4 + j] = relu_f(acc[i][j] + b1[n0 + tx*4 + j]);
        }
    }
}

// ---------------------------------------------------------------------------
// K1 (v3 = R7 structure + XCD pair-decode): bid<512: 128-row x 256-col MFMA
//   GEMM over d2 (K=512). Decode puts path0/path1 blocks with the SAME 128
//   d2-rows adjacently on the SAME XCD (bid%8 round-robin assumption), so
//   path1's A-read hits the per-XCD L2 (working set ~1 MB < 4 MB) and d2
//   HBM traffic halves. path: 0 -> d3 (image) = relu(.@w1+b1),
//   1 -> tv = tanh(.@wv). B via global_load_lds (image); A converted
//   in-loop fp32 -> hi/lo swizzled LDS image (verified R7 state).
// bid>=512: e4[h, ntile] fp32 GEMM (d4 @ W[h][C:]), LDS aliased onto buffers.
// ---------------------------------------------------------------------------
__global__ __launch_bounds__(256, 2) void k1_main(
    const float* __restrict__ d2,
    const unsigned short* __restrict__ w1ts, const unsigned short* __restrict__ wvts,
    const float* __restrict__ b1,
    const float* __restrict__ d4, const float* __restrict__ W,
    unsigned short* __restrict__ d3s, unsigned short* __restrict__ tv,
    float* __restrict__ e4)
{
    __shared__ __align__(16) unsigned short Abuf[128 * 64];   // 16 KB
    __shared__ __align__(16) unsigned short Bbuf[256 * 64];   // 32 KB

    const int tid = threadIdx.x;
    const int bid = blockIdx.x;

    if (bid >= 512) {
        // ---- e4 path (fp32 vector, tiny). Alias LDS onto buffers. ----
        float (*As)[68] = (float(*)[68])&Abuf[0];
        float (*Bs)[68] = (float(*)[68])&Bbuf[0];
        const int idx = bid - 512;
        const int n0 = (idx & 3) * 64;
        const int h  = idx >> 2;
        const float* Wh = W + ((size_t)h * 2 * CC + CC) * CC;
        const int tx = tid & 15, ty = tid >> 4;
        const int lm = tid >> 2, lk4 = (tid & 3) * 4;
        const int bk = tid >> 4, bn4 = (tid & 15) * 4;
        float acc[4][4] = {};
        for (int k0 = 0; k0 < CC; k0 += 16) {
            float4 a = *(const float4*)(d4 + (size_t)lm * CC + k0 + lk4);
            As[lk4+0][lm] = a.x; As[lk4+1][lm] = a.y;
            As[lk4+2][lm] = a.z; As[lk4+3][lm] = a.w;
            *(float4*)&Bs[bk][bn4] = *(const float4*)(Wh + (size_t)(k0+bk)*CC + n0 + bn4);
            __syncthreads();
            #pragma unroll
            for (int kk = 0; kk < 16; ++kk) {
                float4 a4 = *(const float4*)&As[kk][ty*4];
                float4 b4 = *(const float4*)&Bs[kk][tx*4];
                float av[4] = {a4.x, a4.y, a4.z, a4.w};
                float bv[4] = {b4.x, b4.y, b4.z, b4.w};
                #pragma unroll
                for (int i = 0; i < 4; ++i)
                    #pragma unroll
                    for (int j = 0; j < 4; ++j)
                        acc[i][j] = fmaf(av[i], bv[j], acc[i][j]);
            }
            __syncthreads();
        }
        #pragma unroll
        for (int i = 0; i < 4; ++i) {
            int b = ty*4 + i;
            #pragma unroll
            for (int j = 0; j < 4; ++j)
                e4[((size_t)h*BB + b)*CC + n0 + tx*4 + j] = acc[i][j];
        }
        return;
    }

    // ---- main GEMM path: XCD pair-decode ----
    const int cxcd = bid & 7;
    const int jd   = bid >> 3;
    const int path = jd & 1;                 // 0: w1->d3, 1: wv->tv
    const int xb   = (jd >> 1) * 8 + cxcd;   // row-tile 0..255
    const int r0   = xb * 128;
    const int lane = tid & 63, w = tid >> 6;
    const int rowgrp = w & 1, colgrp = w >> 1;
    const int cb = lane & 15, quad = lane >> 4;
    const unsigned short* BT = path ? wvts : w1ts;

    f32x4 acc[4][8];
    f32x4 zero = {0.0f, 0.0f, 0.0f, 0.0f};
    #pragma unroll
    for (int rt = 0; rt < 4; ++rt)
        #pragma unroll
        for (int ct = 0; ct < 8; ++ct) acc[rt][ct] = zero;

    const int ar = tid >> 1, ak = (tid & 1) * 16;   // A staging coords
    const int arx = ar & 7;
    const int g0 = ak >> 3;                          // 0 or 2
    const int phi = (2 * quad) ^ (cb & 7);           // read-side swizzle (hi)

    for (int k0 = 0; k0 < FF; k0 += 32) {
        const int kt = k0 >> 5;
        // stage B: 256 n x 32 k image, 32 KB via global_load_lds (8 x 1KB/wave)
        {
            const unsigned short* Bsrc = BT + (size_t)kt * (CC * 64);
            #pragma unroll
            for (int i = 0; i < 8; ++i) {
                int chunk = i * 4 + w;
                gld16(Bsrc + (size_t)chunk * 512 + lane * 8, &Bbuf[chunk * 512]);
            }
        }
        // stage A: 128 rows x 32 k of d2, fp32 -> hi/lo split, swizzled image
        {
            const float* s = d2 + (size_t)(r0 + ar) * FF + k0 + ak;
            float v[16];
            *(float4*)&v[0]  = *(const float4*)(s);
            *(float4*)&v[4]  = *(const float4*)(s + 4);
            *(float4*)&v[8]  = *(const float4*)(s + 8);
            *(float4*)&v[12] = *(const float4*)(s + 12);
            bf16x8 vh0, vh1, vl0, vl1;
            #pragma unroll
            for (int j = 0; j < 8; ++j) {
                unsigned short h = f2bf(v[j]);
                vh0[j] = (short)h; vl0[j] = (short)f2bf(v[j] - bf2f(h));
                unsigned short h2 = f2bf(v[j+8]);
                vh1[j] = (short)h2; vl1[j] = (short)f2bf(v[j+8] - bf2f(h2));
            }
            unsigned short* Ar = &Abuf[ar * 64];
            *(bf16x8*)&Ar[((2*g0 + 0) ^ arx) * 8] = vh0;
            *(bf16x8*)&Ar[((2*g0 + 1) ^ arx) * 8] = vl0;
            *(bf16x8*)&Ar[((2*g0 + 2) ^ arx) * 8] = vh1;
            *(bf16x8*)&Ar[((2*g0 + 3) ^ arx) * 8] = vl1;
        }
        __syncthreads();
        bf16x8 ahf[4], alf[4];
        #pragma unroll
        for (int rt = 0; rt < 4; ++rt) {
            const unsigned short* Arow = &Abuf[(rowgrp*64 + rt*16 + cb) * 64];
            ahf[rt] = *(const bf16x8*)&Arow[phi * 8];
            alf[rt] = *(const bf16x8*)&Arow[(phi ^ 1) * 8];
        }
        #pragma unroll
        for (int ct = 0; ct < 8; ++ct) {
            const unsigned short* Brow = &Bbuf[(colgrp*128 + ct*16 + cb) * 64];
            bf16x8 bh = *(const bf16x8*)&Brow[phi * 8];
            bf16x8 bl = *(const bf16x8*)&Brow[(phi ^ 1) * 8];
            #pragma unroll
            for (int rt = 0; rt < 4; ++rt) {
                acc[rt][ct] = __builtin_amdgcn_mfma_f32_16x16x32_bf16(ahf[rt], bh, acc[rt][ct], 0, 0, 0);
                acc[rt][ct] = __builtin_amdgcn_mfma_f32_16x16x32_bf16(ahf[rt], bl, acc[rt][ct], 0, 0, 0);
                acc[rt][ct] = __builtin_amdgcn_mfma_f32_16x16x32_bf16(alf[rt], bh, acc[rt][ct], 0, 0, 0);
            }
        }
        __syncthreads();
    }
    // epilogue. C layout: col = ct*16+cb (+colgrp*128), row = rt*16+quad*4+r (+rowgrp*64)
    if (path == 0) {
        float bias[8];
        #pragma unroll
        for (int ct = 0; ct < 8; ++ct) bias[ct] = b1[colgrp*128 + ct*16 + cb];
        #pragma unroll
        for (int rt = 0; rt < 4; ++rt) {
            #pragma unroll
            for (int r = 0; r < 4; ++r) {
                int gr = r0 + rowgrp*64 + rt*16 + quad*4 + r;
                int sxr = gr & 7;
                #pragma unroll
                for (int ct = 0; ct < 8; ++ct) {
                    int c = colgrp*128 + ct*16 + cb;
                    float val = relu_f(acc[rt][ct][r] + bias[ct]);
                    unsigned short hx = f2bf(val);
                    unsigned short lx = f2bf(val - bf2f(hx));
                    int kt = c >> 5;
                    int g = (c >> 3) & 3;
                    size_t rowo = ((size_t)kt * SB + gr) * 64;
                    d3s[rowo + (size_t)((2*g + 0) ^ sxr) * 8 + (c & 7)] = hx;
                    d3s[rowo + (size_t)((2*g + 1) ^ sxr) * 8 + (c & 7)] = lx;
                }
            }
        }
    } else {
        #pragma unroll
        for (int rt = 0; rt < 4; ++rt) {
            #pragma unroll
            for (int r = 0; r < 4; ++r) {
                int gr = r0 + rowgrp*64 + rt*16 + quad*4 + r;
                int s = gr >> 6, b = gr & 63;
                #pragma unroll
                for (int ct = 0; ct < 8; ++ct) {
                    int c = colgrp*128 + ct*16 + cb;
                    tv[((size_t)b * SS + s) * CC + c] = f2bf(fast_tanh(acc[rt][ct][r]));
                }
            }
        }
    }
}

// ---------------------------------------------------------------------------
// K3 (= R7 verified: R1 structure + XCD-grouping decode + launch_bounds(256,2)):
// atts[h,b,s] = sum_c P[h,c]*tanh((d3@Wt[h])[row,c] + e4[h,b,c]).
// Block: 128 rows x 256 cols, one head; A+B via global_load_lds from
// pre-swizzled images; LDS 48 KB (red aliased onto Abuf). VGPR 108,
// 2 blocks/CU, FETCH ~28 MB (verified R7: 124 us).
// ---------------------------------------------------------------------------
__global__ __launch_bounds__(256, 2) void k3_atts(
    const unsigned short* __restrict__ d3s, const unsigned short* __restrict__ Wts,
    const float* __restrict__ e4, const float* __restrict__ P,
    float* __restrict__ atts)
{
    __shared__ __align__(16) unsigned short Abuf[128 * 64];   // 16 KB
    __shared__ __align__(16) unsigned short Bbuf[256 * 64];   // 32 KB
    float (*red)[128] = (float(*)[128])&Abuf[0];  // aliased; live only post-K-loop

    const int tid = threadIdx.x;
    const int lane = tid & 63, w = tid >> 6;
    const int bid = blockIdx.x;
    // bijective XCD-grouping decode (assumes XCD = bid % 8 round-robin)
    const int cxcd = bid & 7;
    const int jj   = bid >> 3;
    const int h    = jj & 7;
    const int xb   = (jj >> 3) * 8 + cxcd;     // row-block 0..255
    const int r0   = xb * 128;
    const int rowgrp = w & 1, colgrp = w >> 1;
    const int cb = lane & 15, quad = lane >> 4;
    const int phi = (2 * quad) ^ (cb & 7);

    const unsigned short* Wh = Wts + (size_t)h * (8 * CC * 64);

    f32x4 acc[4][8];
    f32x4 zero = {0.0f, 0.0f, 0.0f, 0.0f};
    #pragma unroll
    for (int rt = 0; rt < 4; ++rt)
        #pragma unroll
        for (int ct = 0; ct < 8; ++ct) acc[rt][ct] = zero;

    for (int kt = 0; kt < 8; ++kt) {
        // stage A: 128 rows x 32 k image (16 KB), 4 x 1KB per wave
        {
            const unsigned short* Asrc = d3s + ((size_t)kt * SB + r0) * 64;
            #pragma unroll
            for (int i = 0; i < 4; ++i) {
                int chunk = i * 4 + w;
                gld16(Asrc + (size_t)chunk * 512 + lane * 8, &Abuf[chunk * 512]);
            }
        }
        // stage B: 256 n x 32 k image (32 KB), 8 x 1KB per wave
        {
            const unsigned short* Bsrc = Wh + (size_t)kt * (CC * 64);
            #pragma unroll
            for (int i = 0; i < 8; ++i) {
                int chunk = i * 4 + w;
                gld16(Bsrc + (size_t)chunk * 512 + lane * 8, &Bbuf[chunk * 512]);
            }
        }
        __syncthreads();   // drains vmcnt -> LDS image ready
        bf16x8 ahf[4], alf[4];
        #pragma unroll
        for (int rt = 0; rt < 4; ++rt) {
            const unsigned short* Arow = &Abuf[(rowgrp*64 + rt*16 + cb) * 64];
            ahf[rt] = *(const bf16x8*)&Arow[phi * 8];
            alf[rt] = *(const bf16x8*)&Arow[(phi ^ 1) * 8];
        }
        #pragma unroll
        for (int ct = 0; ct < 8; ++ct) {
            const unsigned short* Brow = &Bbuf[(colgrp*128 + ct*16 + cb) * 64];
            bf16x8 bh = *(const bf16x8*)&Brow[phi * 8];
            bf16x8 bl = *(const bf16x8*)&Brow[(phi ^ 1) * 8];
            #pragma unroll
            for (int rt = 0; rt < 4; ++rt) {
                acc[rt][ct] = __builtin_amdgcn_mfma_f32_16x16x32_bf16(ahf[rt], bh, acc[rt][ct], 0, 0, 0);
                acc[rt][ct] = __builtin_amdgcn_mfma_f32_16x16x32_bf16(ahf[rt], bl, acc[rt][ct], 0, 0, 0);
                acc[rt][ct] = __builtin_amdgcn_mfma_f32_16x16x32_bf16(alf[rt], bh, acc[rt][ct], 0, 0, 0);
            }
        }
        __syncthreads();
    }
    // epilogue: tanh + P-dot over this wave's 128 cols, then reduce.
    // (red aliases Abuf; all Abuf reads completed before the last barrier.)
    float Pv[8];
    #pragma unroll
    for (int ct = 0; ct < 8; ++ct) Pv[ct] = P[(size_t)h * CC + colgrp*128 + ct*16 + cb];
    #pragma unroll
    for (int rt = 0; rt < 4; ++rt) {
        #pragma unroll
        for (int r = 0; r < 4; ++r) {
            int b = rt*16 + quad*4 + r;     // batch index (mod 64)
            const float* e4p = e4 + ((size_t)h * BB + b) * CC + colgrp*128 + cb;
            float part = 0.0f;
            #pragma unroll
            for (int ct = 0; ct < 8; ++ct) {
                float u = acc[rt][ct][r] + e4p[ct*16];
                part = fmaf(Pv[ct], fast_tanh(u), part);
            }
            part += __shfl_xor(part, 1); part += __shfl_xor(part, 2);
            part += __shfl_xor(part, 4); part += __shfl_xor(part, 8);
            if (cb == 0) red[colgrp][rowgrp*64 + b] = part;
        }
    }
    __syncthreads();
    if (tid < 128) {
        float v = red[0][tid] + red[1][tid];
        int gr = r0 + tid;
        int s = gr >> 6, b = gr & 63;
        atts[((size_t)h * BB + b) * SS + s] = v;
    }
}

// ---------------------------------------------------------------------------
// K456: per b: softmax over s (8 heads) + vs = scores.tv + out = relu(vs@wcc+bcc)
// ---------------------------------------------------------------------------
__global__ __launch_bounds__(256) void k456_out(
    const float* __restrict__ atts, const unsigned short* __restrict__ tv,
    const float* __restrict__ wcc, const float* __restrict__ bcc,
    float* __restrict__ out)
{
    __shared__ float sc[HH][SS];       // 16 KB
    __shared__ float red[4][2048];     // 32 KB
    const int b = blockIdx.x;
    const int tid = threadIdx.x;
    const int lane = tid & 63, w = tid >> 6;

    for (int i = tid; i < HH*SS; i += 256) {
        int h = i >> 9, s = i & 511;
        sc[h][s] = atts[((size_t)h*BB + b)*SS + s];
    }
    __syncthreads();
    // softmax: wave w handles heads 2w, 2w+1
    #pragma unroll
    for (int t = 0; t < 2; ++t) {
        int hh = w*2 + t;
        float x[8];
        #pragma unroll
        for (int j = 0; j < 8; ++j) x[j] = sc[hh][j*64 + lane];
        float m = x[0];
        #pragma unroll
        for (int j = 1; j < 8; ++j) m = fmaxf(m, x[j]);
        #pragma unroll
        for (int d = 1; d < 64; d <<= 1) m = fmaxf(m, __shfl_xor(m, d));
        float sum = 0.0f;
        #pragma unroll
        for (int j = 0; j < 8; ++j) { x[j] = __expf(x[j] - m); sum += x[j]; }
        #pragma unroll
        for (int d = 1; d < 64; d <<= 1) sum += __shfl_xor(sum, d);
        float inv = 1.0f / sum;
        #pragma unroll
        for (int j = 0; j < 8; ++j) sc[hh][j*64 + lane] = x[j] * inv;
    }
    __syncthreads();
    // vs: stripe = s-range of 128, each lane owns 4 c
    {
        const int cl = tid & 63, stripe = tid >> 6;
        const int c0 = cl * 4;
        const unsigned short* tvb = tv + ((size_t)b * SS + stripe * 128) * CC + c0;
        float acc[HH][4] = {};
        for (int si = 0; si < 128; ++si) {
            uint2 u = *(const uint2*)(tvb + (size_t)si * CC);
            float x0 = bf2f((unsigned short)(u.x));
            float x1 = bf2f((unsigned short)(u.x >> 16));
            float x2 = bf2f((unsigned short)(u.y));
            float x3 = bf2f((unsigned short)(u.y >> 16));
            int s = stripe * 128 + si;
            #pragma unroll
            for (int h = 0; h < HH; ++h) {
                float wgt = sc[h][s];
                acc[h][0] = fmaf(wgt, x0, acc[h][0]);
                acc[h][1] = fmaf(wgt, x1, acc[h][1]);
                acc[h][2] = fmaf(wgt, x2, acc[h][2]);
                acc[h][3] = fmaf(wgt, x3, acc[h][3]);
            }
        }
        #pragma unroll
        for (int h = 0; h < HH; ++h)
            #pragma unroll
            for (int j = 0; j < 4; ++j)
                red[stripe][h*256 + c0 + j] = acc[h][j];
    }
    __syncthreads();
    for (int i = tid; i < 2048; i += 256)
        red[0][i] = red[0][i] + red[1][i] + red[2][i] + red[3][i];
    __syncthreads();
    // out: 2 threads per output column
    {
        const int n = tid & 127, half = tid >> 7;
        float o = 0.0f;
        const int kbase = half * 1024;
        for (int k = 0; k < 1024; ++k)
            o = fmaf(red[0][kbase + k], wcc[(size_t)(kbase + k) * 128 + n], o);
        float* r2 = &sc[0][0];
        r2[half * 128 + n] = o;
    }
    __syncthreads();
    if (tid < 128)
        out[(size_t)b * 128 + tid] = relu_f(sc[0][tid] + sc[0][128 + tid] + bcc[tid]);
}

// ---------------------------------------------------------------------------
extern "C" void kernel_launch(void* const* d_in, const int* in_sizes, int n_in,
                              void* d_out, int out_size, void* d_ws, size_t ws_size,
                              hipStream_t stream)
{
    (void)in_sizes; (void)n_in; (void)out_size; (void)ws_size;
    const float* d1  = (const float*)d_in[0];
    const float* d2  = (const float*)d_in[1];
    const float* w1  = (const float*)d_in[2];
    const float* b1  = (const float*)d_in[3];
    const float* W   = (const float*)d_in[4];
    const float* P   = (const float*)d_in[5];
    const float* wv  = (const float*)d_in[6];
    const float* wcc = (const float*)d_in[7];
    const float* bcc = (const float*)d_in[8];
    float* out = (float*)d_out;

    char* p = (char*)d_ws;
    unsigned short* d3s  = (unsigned short*)p; p += (size_t)8 * SB * 64 * 2;       // 33.55 MB
    unsigned short* tv   = (unsigned short*)p; p += (size_t)SB * CC * 2;           // 16.78 MB
    unsigned short* w1ts = (unsigned short*)p; p += (size_t)16 * CC * 64 * 2;      // 512 KB
    unsigned short* wvts = (unsigned short*)p; p += (size_t)16 * CC * 64 * 2;      // 512 KB
    unsigned short* Wts  = (unsigned short*)p; p += (size_t)HH * 8 * CC * 64 * 2;  // 2 MB
    float* d4   = (float*)p;  p += (size_t)BB * CC * 4;
    float* e4   = (float*)p;  p += (size_t)HH * BB * CC * 4;
    float* atts = (float*)p;  p += (size_t)HH * BB * SS * 4;

    p_prep   <<<dim3(196),       256, 0, stream>>>(w1, wv, W, d1, b1,
                  w1ts, wvts, Wts, d4);
    k1_main  <<<dim3(544),       256, 0, stream>>>(d2, w1ts, wvts, b1, d4, W,
                  d3s, tv, e4);
    k3_atts  <<<dim3(2048),      256, 0, stream>>>(d3s, Wts, e4, P, atts);
    k456_out <<<dim3(BB),        256, 0, stream>>>(atts, tv, wcc, bcc, out);
}

// Round 10
// 348.702 us; speedup vs baseline: 1.1047x; 1.0160x over previous
//
#include <hip/hip_runtime.h>
#include <cstddef>
#include <cstdint>

// Problem constants
#define HH 8
#define FF 512
#define CC 256
#define SS 512
#define BB 64
#define SB (SS*BB)   // 32768

typedef __attribute__((ext_vector_type(4))) float f32x4;
typedef __attribute__((ext_vector_type(8))) short bf16x8;

typedef __attribute__((address_space(1))) unsigned int gu32_t;
typedef __attribute__((address_space(3))) unsigned int lu32_t;

// Async global->LDS, 16B per lane. LDS dest = wave-uniform base + lane*16.
__device__ __forceinline__ void gld16(const void* gp, void* lp) {
    __builtin_amdgcn_global_load_lds((gu32_t*)gp, (lu32_t*)lp, 16, 0, 0);
}

__device__ __forceinline__ float fast_tanh(float x) {
    float e = __expf(2.0f * x);
    return 1.0f - 2.0f / (e + 1.0f);
}
__device__ __forceinline__ float relu_f(float x) { return fmaxf(x, 0.0f); }

__device__ __forceinline__ unsigned short f2bf(float x) {
    unsigned u = __float_as_uint(x);
    unsigned r = u + 0x7FFFu + ((u >> 16) & 1u);
    return (unsigned short)(r >> 16);
}
__device__ __forceinline__ float bf2f(unsigned short h) {
    return __uint_as_float(((unsigned)h) << 16);
}

// ---------------------------------------------------------------------------
// Swizzled operand-tile format ("image" format), shared by all MFMA GEMMs:
//   For a logical matrix of rows n (output dim) x k (reduce dim), split fp32
//   into bf16 hi/lo. Layout: [kt = k/32][n][p][8 bf16], where for k-granule
//   g = (k>>3)&3 and h in {hi=0, lo=1}: q = 2g+h, p = q ^ (n&7).
//   Row block = 128 B. This is EXACTLY the LDS image each k-step wants, so
//   staging is linear global_load_lds; ds_read uses p = (2*quad+h) ^ (cb&7).
// ---------------------------------------------------------------------------

// ---------------------------------------------------------------------------
// PREP: bid<192: transpose+split of w1/wv (-> 16 kt planes) and W[h] rows
//       0..C-1 (-> 8 kt planes), emitted in image format.
//       bid 192..195: d4 = relu(d1@w1+b1) (fp32, 64x64 tile each).
// ---------------------------------------------------------------------------
__global__ __launch_bounds__(256) void p_prep(
    const float* __restrict__ w1, const float* __restrict__ wv,
    const float* __restrict__ W, const float* __restrict__ d1,
    const float* __restrict__ b1,
    unsigned short* __restrict__ w1ts, unsigned short* __restrict__ wvts,
    unsigned short* __restrict__ Wts, float* __restrict__ d4)
{
    __shared__ float T[64][65];
    __shared__ float As[16][68];
    __shared__ float Bs[16][68];
    const int tid = threadIdx.x;
    const int bid = blockIdx.x;
    if (bid < 192) {
        const float* src;
        unsigned short* dst;
        int kt64, nt;
        if (bid < 64) {
            int m = bid >> 5;            // 0: w1, 1: wv
            int t = bid & 31;
            kt64 = t >> 2; nt = t & 3;
            src = m ? wv : w1;
            dst = m ? wvts : w1ts;
        } else {
            int t = bid - 64;
            int h = t >> 4; int tt = t & 15;
            kt64 = tt >> 2; nt = tt & 3;
            src = W + (size_t)h * 2 * CC * CC;
            dst = Wts + (size_t)h * 8 * CC * 64;
        }
        const int k0 = kt64 * 64, n0 = nt * 64;
        #pragma unroll
        for (int jj = 0; jj < 4; ++jj) {
            int i = (tid >> 4) + jj * 16;
            int j = (tid & 15) * 4;
            float4 v = *(const float4*)(src + (size_t)(k0 + i) * CC + n0 + j);
            T[i][j] = v.x; T[i][j+1] = v.y; T[i][j+2] = v.z; T[i][j+3] = v.w;
        }
        __syncthreads();
        // write: each thread owns one n, 16 consecutive k (2 granules)
        {
            const int n_local = tid & 63;
            const int kg = (tid >> 6) * 16;
            const int n_abs = n0 + n_local;
            const int sxn = n_abs & 7;
            #pragma unroll
            for (int j = 0; j < 2; ++j) {
                const int kbase = kg + j * 8;
                const int k_abs = k0 + kbase;
                const int kt = k_abs >> 5;
                const int g = (k_abs >> 3) & 3;
                bf16x8 hv8, lv8;
                #pragma unroll
                for (int q = 0; q < 8; ++q) {
                    float x = T[kbase + q][n_local];
                    unsigned short hx = f2bf(x);
                    hv8[q] = (short)hx;
                    lv8[q] = (short)f2bf(x - bf2f(hx));
                }
                size_t rowo = ((size_t)kt * CC + n_abs) * 64;
                *(bf16x8*)(dst + rowo + (size_t)((2*g + 0) ^ sxn) * 8) = hv8;
                *(bf16x8*)(dst + rowo + (size_t)((2*g + 1) ^ sxn) * 8) = lv8;
            }
        }
    } else {
        // d4 tile: 64 rows x 64 cols (n0), fp32 vector GEMM
        const int n0 = (bid - 192) * 64;
        const int tx = tid & 15, ty = tid >> 4;
        const int lm = tid >> 2, lk4 = (tid & 3) * 4;
        const int bk = tid >> 4, bn4 = (tid & 15) * 4;
        float acc[4][4] = {};
        for (int k0 = 0; k0 < FF; k0 += 16) {
            float4 a = *(const float4*)(d1 + (size_t)lm * FF + k0 + lk4);
            As[lk4+0][lm] = a.x; As[lk4+1][lm] = a.y;
            As[lk4+2][lm] = a.z; As[lk4+3][lm] = a.w;
            *(float4*)&Bs[bk][bn4] = *(const float4*)(w1 + (size_t)(k0+bk)*CC + n0 + bn4);
            __syncthreads();
            #pragma unroll
            for (int kk = 0; kk < 16; ++kk) {
                float4 a4 = *(const float4*)&As[kk][ty*4];
                float4 b4 = *(const float4*)&Bs[kk][tx*4];
                float av[4] = {a4.x, a4.y, a4.z, a4.w};
                float bv[4] = {b4.x, b4.y, b4.z, b4.w};
                #pragma unroll
                for (int i = 0; i < 4; ++i)
                    #pragma unroll
                    for (int j = 0; j < 4; ++j)
                        acc[i][j] = fmaf(av[i], bv[j], acc[i][j]);
            }
            __syncthreads();
        }
        #pragma unroll
        for (int i = 0; i < 4; ++i) {
            int row = ty*4 + i;
            #pragma unroll
            for (int j = 0; j < 4; ++j)
                d4[(size_t)row*CC + n0 + tx*4 + j] = relu_f(acc[i][j] + b1[n0 + tx*4 + j]);
        }
    }
}

// ---------------------------------------------------------------------------
// K1 (v3 = R7 structure + XCD pair-decode): bid<512: 128-row x 256-col MFMA
//   GEMM over d2 (K=512). Decode puts path0/path1 blocks with the SAME 128
//   d2-rows adjacently on the SAME XCD (bid%8 round-robin assumption), so
//   path1's A-read hits the per-XCD L2 (working set ~1 MB < 4 MB) and d2
//   HBM traffic halves. path: 0 -> d3 (image) = relu(.@w1+b1),
//   1 -> tv = tanh(.@wv). B via global_load_lds (image); A converted
//   in-loop fp32 -> hi/lo swizzled LDS image (verified R7 state).
// bid>=512: e4[h, ntile] fp32 GEMM (d4 @ W[h][C:]), LDS aliased onto buffers.
// ---------------------------------------------------------------------------
__global__ __launch_bounds__(256, 2) void k1_main(
    const float* __restrict__ d2,
    const unsigned short* __restrict__ w1ts, const unsigned short* __restrict__ wvts,
    const float* __restrict__ b1,
    const float* __restrict__ d4, const float* __restrict__ W,
    unsigned short* __restrict__ d3s, unsigned short* __restrict__ tv,
    float* __restrict__ e4)
{
    __shared__ __align__(16) unsigned short Abuf[128 * 64];   // 16 KB
    __shared__ __align__(16) unsigned short Bbuf[256 * 64];   // 32 KB

    const int tid = threadIdx.x;
    const int bid = blockIdx.x;

    if (bid >= 512) {
        // ---- e4 path (fp32 vector, tiny). Alias LDS onto buffers. ----
        float (*As)[68] = (float(*)[68])&Abuf[0];
        float (*Bs)[68] = (float(*)[68])&Bbuf[0];
        const int idx = bid - 512;
        const int n0 = (idx & 3) * 64;
        const int h  = idx >> 2;
        const float* Wh = W + ((size_t)h * 2 * CC + CC) * CC;
        const int tx = tid & 15, ty = tid >> 4;
        const int lm = tid >> 2, lk4 = (tid & 3) * 4;
        const int bk = tid >> 4, bn4 = (tid & 15) * 4;
        float acc[4][4] = {};
        for (int k0 = 0; k0 < CC; k0 += 16) {
            float4 a = *(const float4*)(d4 + (size_t)lm * CC + k0 + lk4);
            As[lk4+0][lm] = a.x; As[lk4+1][lm] = a.y;
            As[lk4+2][lm] = a.z; As[lk4+3][lm] = a.w;
            *(float4*)&Bs[bk][bn4] = *(const float4*)(Wh + (size_t)(k0+bk)*CC + n0 + bn4);
            __syncthreads();
            #pragma unroll
            for (int kk = 0; kk < 16; ++kk) {
                float4 a4 = *(const float4*)&As[kk][ty*4];
                float4 b4 = *(const float4*)&Bs[kk][tx*4];
                float av[4] = {a4.x, a4.y, a4.z, a4.w};
                float bv[4] = {b4.x, b4.y, b4.z, b4.w};
                #pragma unroll
                for (int i = 0; i < 4; ++i)
                    #pragma unroll
                    for (int j = 0; j < 4; ++j)
                        acc[i][j] = fmaf(av[i], bv[j], acc[i][j]);
            }
            __syncthreads();
        }
        #pragma unroll
        for (int i = 0; i < 4; ++i) {
            int b = ty*4 + i;
            #pragma unroll
            for (int j = 0; j < 4; ++j)
                e4[((size_t)h*BB + b)*CC + n0 + tx*4 + j] = acc[i][j];
        }
        return;
    }

    // ---- main GEMM path: XCD pair-decode ----
    const int cxcd = bid & 7;
    const int jd   = bid >> 3;
    const int path = jd & 1;                 // 0: w1->d3, 1: wv->tv
    const int xb   = (jd >> 1) * 8 + cxcd;   // row-tile 0..255
    const int r0   = xb * 128;
    const int lane = tid & 63, w = tid >> 6;
    const int rowgrp = w & 1, colgrp = w >> 1;
    const int cb = lane & 15, quad = lane >> 4;
    const unsigned short* BT = path ? wvts : w1ts;

    f32x4 acc[4][8];
    f32x4 zero = {0.0f, 0.0f, 0.0f, 0.0f};
    #pragma unroll
    for (int rt = 0; rt < 4; ++rt)
        #pragma unroll
        for (int ct = 0; ct < 8; ++ct) acc[rt][ct] = zero;

    const int ar = tid >> 1, ak = (tid & 1) * 16;   // A staging coords
    const int arx = ar & 7;
    const int g0 = ak >> 3;                          // 0 or 2
    const int phi = (2 * quad) ^ (cb & 7);           // read-side swizzle (hi)

    for (int k0 = 0; k0 < FF; k0 += 32) {
        const int kt = k0 >> 5;
        // stage B: 256 n x 32 k image, 32 KB via global_load_lds (8 x 1KB/wave)
        {
            const unsigned short* Bsrc = BT + (size_t)kt * (CC * 64);
            #pragma unroll
            for (int i = 0; i < 8; ++i) {
                int chunk = i * 4 + w;
                gld16(Bsrc + (size_t)chunk * 512 + lane * 8, &Bbuf[chunk * 512]);
            }
        }
        // stage A: 128 rows x 32 k of d2, fp32 -> hi/lo split, swizzled image
        {
            const float* s = d2 + (size_t)(r0 + ar) * FF + k0 + ak;
            float v[16];
            *(float4*)&v[0]  = *(const float4*)(s);
            *(float4*)&v[4]  = *(const float4*)(s + 4);
            *(float4*)&v[8]  = *(const float4*)(s + 8);
            *(float4*)&v[12] = *(const float4*)(s + 12);
            bf16x8 vh0, vh1, vl0, vl1;
            #pragma unroll
            for (int j = 0; j < 8; ++j) {
                unsigned short h = f2bf(v[j]);
                vh0[j] = (short)h; vl0[j] = (short)f2bf(v[j] - bf2f(h));
                unsigned short h2 = f2bf(v[j+8]);
                vh1[j] = (short)h2; vl1[j] = (short)f2bf(v[j+8] - bf2f(h2));
            }
            unsigned short* Ar = &Abuf[ar * 64];
            *(bf16x8*)&Ar[((2*g0 + 0) ^ arx) * 8] = vh0;
            *(bf16x8*)&Ar[((2*g0 + 1) ^ arx) * 8] = vl0;
            *(bf16x8*)&Ar[((2*g0 + 2) ^ arx) * 8] = vh1;
            *(bf16x8*)&Ar[((2*g0 + 3) ^ arx) * 8] = vl1;
        }
        __syncthreads();
        bf16x8 ahf[4], alf[4];
        #pragma unroll
        for (int rt = 0; rt < 4; ++rt) {
            const unsigned short* Arow = &Abuf[(rowgrp*64 + rt*16 + cb) * 64];
            ahf[rt] = *(const bf16x8*)&Arow[phi * 8];
            alf[rt] = *(const bf16x8*)&Arow[(phi ^ 1) * 8];
        }
        #pragma unroll
        for (int ct = 0; ct < 8; ++ct) {
            const unsigned short* Brow = &Bbuf[(colgrp*128 + ct*16 + cb) * 64];
            bf16x8 bh = *(const bf16x8*)&Brow[phi * 8];
            bf16x8 bl = *(const bf16x8*)&Brow[(phi ^ 1) * 8];
            #pragma unroll
            for (int rt = 0; rt < 4; ++rt) {
                acc[rt][ct] = __builtin_amdgcn_mfma_f32_16x16x32_bf16(ahf[rt], bh, acc[rt][ct], 0, 0, 0);
                acc[rt][ct] = __builtin_amdgcn_mfma_f32_16x16x32_bf16(ahf[rt], bl, acc[rt][ct], 0, 0, 0);
                acc[rt][ct] = __builtin_amdgcn_mfma_f32_16x16x32_bf16(alf[rt], bh, acc[rt][ct], 0, 0, 0);
            }
        }
        __syncthreads();
    }
    // epilogue. C layout: col = ct*16+cb (+colgrp*128), row = rt*16+quad*4+r (+rowgrp*64)
    if (path == 0) {
        float bias[8];
        #pragma unroll
        for (int ct = 0; ct < 8; ++ct) bias[ct] = b1[colgrp*128 + ct*16 + cb];
        #pragma unroll
        for (int rt = 0; rt < 4; ++rt) {
            #pragma unroll
            for (int r = 0; r < 4; ++r) {
                int gr = r0 + rowgrp*64 + rt*16 + quad*4 + r;
                int sxr = gr & 7;
                #pragma unroll
                for (int ct = 0; ct < 8; ++ct) {
                    int c = colgrp*128 + ct*16 + cb;
                    float val = relu_f(acc[rt][ct][r] + bias[ct]);
                    unsigned short hx = f2bf(val);
                    unsigned short lx = f2bf(val - bf2f(hx));
                    int kt = c >> 5;
                    int g = (c >> 3) & 3;
                    size_t rowo = ((size_t)kt * SB + gr) * 64;
                    d3s[rowo + (size_t)((2*g + 0) ^ sxr) * 8 + (c & 7)] = hx;
                    d3s[rowo + (size_t)((2*g + 1) ^ sxr) * 8 + (c & 7)] = lx;
                }
            }
        }
    } else {
        #pragma unroll
        for (int rt = 0; rt < 4; ++rt) {
            #pragma unroll
            for (int r = 0; r < 4; ++r) {
                int gr = r0 + rowgrp*64 + rt*16 + quad*4 + r;
                int s = gr >> 6, b = gr & 63;
                #pragma unroll
                for (int ct = 0; ct < 8; ++ct) {
                    int c = colgrp*128 + ct*16 + cb;
                    tv[((size_t)b * SS + s) * CC + c] = f2bf(fast_tanh(acc[rt][ct][r]));
                }
            }
        }
    }
}

// ---------------------------------------------------------------------------
// K3 (= R7 verified: R1 structure + XCD-grouping decode + launch_bounds(256,2)):
// atts[h,b,s] = sum_c P[h,c]*tanh((d3@Wt[h])[row,c] + e4[h,b,c]).
// Block: 128 rows x 256 cols, one head; A+B via global_load_lds from
// pre-swizzled images; LDS 48 KB (red aliased onto Abuf). VGPR 108,
// 2 blocks/CU, FETCH ~28 MB (verified R7: 124 us; R9 re-measure: 156 us
// with all rate counters scaled x0.80 at identical work/bytes -> suspected
// clock-state variance; this round is a deliberate A/A re-measure).
// ---------------------------------------------------------------------------
__global__ __launch_bounds__(256, 2) void k3_atts(
    const unsigned short* __restrict__ d3s, const unsigned short* __restrict__ Wts,
    const float* __restrict__ e4, const float* __restrict__ P,
    float* __restrict__ atts)
{
    __shared__ __align__(16) unsigned short Abuf[128 * 64];   // 16 KB
    __shared__ __align__(16) unsigned short Bbuf[256 * 64];   // 32 KB
    float (*red)[128] = (float(*)[128])&Abuf[0];  // aliased; live only post-K-loop

    const int tid = threadIdx.x;
    const int lane = tid & 63, w = tid >> 6;
    const int bid = blockIdx.x;
    // bijective XCD-grouping decode (assumes XCD = bid % 8 round-robin)
    const int cxcd = bid & 7;
    const int jj   = bid >> 3;
    const int h    = jj & 7;
    const int xb   = (jj >> 3) * 8 + cxcd;     // row-block 0..255
    const int r0   = xb * 128;
    const int rowgrp = w & 1, colgrp = w >> 1;
    const int cb = lane & 15, quad = lane >> 4;
    const int phi = (2 * quad) ^ (cb & 7);

    const unsigned short* Wh = Wts + (size_t)h * (8 * CC * 64);

    f32x4 acc[4][8];
    f32x4 zero = {0.0f, 0.0f, 0.0f, 0.0f};
    #pragma unroll
    for (int rt = 0; rt < 4; ++rt)
        #pragma unroll
        for (int ct = 0; ct < 8; ++ct) acc[rt][ct] = zero;

    for (int kt = 0; kt < 8; ++kt) {
        // stage A: 128 rows x 32 k image (16 KB), 4 x 1KB per wave
        {
            const unsigned short* Asrc = d3s + ((size_t)kt * SB + r0) * 64;
            #pragma unroll
            for (int i = 0; i < 4; ++i) {
                int chunk = i * 4 + w;
                gld16(Asrc + (size_t)chunk * 512 + lane * 8, &Abuf[chunk * 512]);
            }
        }
        // stage B: 256 n x 32 k image (32 KB), 8 x 1KB per wave
        {
            const unsigned short* Bsrc = Wh + (size_t)kt * (CC * 64);
            #pragma unroll
            for (int i = 0; i < 8; ++i) {
                int chunk = i * 4 + w;
                gld16(Bsrc + (size_t)chunk * 512 + lane * 8, &Bbuf[chunk * 512]);
            }
        }
        __syncthreads();   // drains vmcnt -> LDS image ready
        bf16x8 ahf[4], alf[4];
        #pragma unroll
        for (int rt = 0; rt < 4; ++rt) {
            const unsigned short* Arow = &Abuf[(rowgrp*64 + rt*16 + cb) * 64];
            ahf[rt] = *(const bf16x8*)&Arow[phi * 8];
            alf[rt] = *(const bf16x8*)&Arow[(phi ^ 1) * 8];
        }
        #pragma unroll
        for (int ct = 0; ct < 8; ++ct) {
            const unsigned short* Brow = &Bbuf[(colgrp*128 + ct*16 + cb) * 64];
            bf16x8 bh = *(const bf16x8*)&Brow[phi * 8];
            bf16x8 bl = *(const bf16x8*)&Brow[(phi ^ 1) * 8];
            #pragma unroll
            for (int rt = 0; rt < 4; ++rt) {
                acc[rt][ct] = __builtin_amdgcn_mfma_f32_16x16x32_bf16(ahf[rt], bh, acc[rt][ct], 0, 0, 0);
                acc[rt][ct] = __builtin_amdgcn_mfma_f32_16x16x32_bf16(ahf[rt], bl, acc[rt][ct], 0, 0, 0);
                acc[rt][ct] = __builtin_amdgcn_mfma_f32_16x16x32_bf16(alf[rt], bh, acc[rt][ct], 0, 0, 0);
            }
        }
        __syncthreads();
    }
    // epilogue: tanh + P-dot over this wave's 128 cols, then reduce.
    // (red aliases Abuf; all Abuf reads completed before the last barrier.)
    float Pv[8];
    #pragma unroll
    for (int ct = 0; ct < 8; ++ct) Pv[ct] = P[(size_t)h * CC + colgrp*128 + ct*16 + cb];
    #pragma unroll
    for (int rt = 0; rt < 4; ++rt) {
        #pragma unroll
        for (int r = 0; r < 4; ++r) {
            int b = rt*16 + quad*4 + r;     // batch index (mod 64)
            const float* e4p = e4 + ((size_t)h * BB + b) * CC + colgrp*128 + cb;
            float part = 0.0f;
            #pragma unroll
            for (int ct = 0; ct < 8; ++ct) {
                float u = acc[rt][ct][r] + e4p[ct*16];
                part = fmaf(Pv[ct], fast_tanh(u), part);
            }
            part += __shfl_xor(part, 1); part += __shfl_xor(part, 2);
            part += __shfl_xor(part, 4); part += __shfl_xor(part, 8);
            if (cb == 0) red[colgrp][rowgrp*64 + b] = part;
        }
    }
    __syncthreads();
    if (tid < 128) {
        float v = red[0][tid] + red[1][tid];
        int gr = r0 + tid;
        int s = gr >> 6, b = gr & 63;
        atts[((size_t)h * BB + b) * SS + s] = v;
    }
}

// ---------------------------------------------------------------------------
// K456: per b: softmax over s (8 heads) + vs = scores.tv + out = relu(vs@wcc+bcc)
// ---------------------------------------------------------------------------
__global__ __launch_bounds__(256) void k456_out(
    const float* __restrict__ atts, const unsigned short* __restrict__ tv,
    const float* __restrict__ wcc, const float* __restrict__ bcc,
    float* __restrict__ out)
{
    __shared__ float sc[HH][SS];       // 16 KB
    __shared__ float red[4][2048];     // 32 KB
    const int b = blockIdx.x;
    const int tid = threadIdx.x;
    const int lane = tid & 63, w = tid >> 6;

    for (int i = tid; i < HH*SS; i += 256) {
        int h = i >> 9, s = i & 511;
        sc[h][s] = atts[((size_t)h*BB + b)*SS + s];
    }
    __syncthreads();
    // softmax: wave w handles heads 2w, 2w+1
    #pragma unroll
    for (int t = 0; t < 2; ++t) {
        int hh = w*2 + t;
        float x[8];
        #pragma unroll
        for (int j = 0; j < 8; ++j) x[j] = sc[hh][j*64 + lane];
        float m = x[0];
        #pragma unroll
        for (int j = 1; j < 8; ++j) m = fmaxf(m, x[j]);
        #pragma unroll
        for (int d = 1; d < 64; d <<= 1) m = fmaxf(m, __shfl_xor(m, d));
        float sum = 0.0f;
        #pragma unroll
        for (int j = 0; j < 8; ++j) { x[j] = __expf(x[j] - m); sum += x[j]; }
        #pragma unroll
        for (int d = 1; d < 64; d <<= 1) sum += __shfl_xor(sum, d);
        float inv = 1.0f / sum;
        #pragma unroll
        for (int j = 0; j < 8; ++j) sc[hh][j*64 + lane] = x[j] * inv;
    }
    __syncthreads();
    // vs: stripe = s-range of 128, each lane owns 4 c
    {
        const int cl = tid & 63, stripe = tid >> 6;
        const int c0 = cl * 4;
        const unsigned short* tvb = tv + ((size_t)b * SS + stripe * 128) * CC + c0;
        float acc[HH][4] = {};
        for (int si = 0; si < 128; ++si) {
            uint2 u = *(const uint2*)(tvb + (size_t)si * CC);
            float x0 = bf2f((unsigned short)(u.x));
            float x1 = bf2f((unsigned short)(u.x >> 16));
            float x2 = bf2f((unsigned short)(u.y));
            float x3 = bf2f((unsigned short)(u.y >> 16));
            int s = stripe * 128 + si;
            #pragma unroll
            for (int h = 0; h < HH; ++h) {
                float wgt = sc[h][s];
                acc[h][0] = fmaf(wgt, x0, acc[h][0]);
                acc[h][1] = fmaf(wgt, x1, acc[h][1]);
                acc[h][2] = fmaf(wgt, x2, acc[h][2]);
                acc[h][3] = fmaf(wgt, x3, acc[h][3]);
            }
        }
        #pragma unroll
        for (int h = 0; h < HH; ++h)
            #pragma unroll
            for (int j = 0; j < 4; ++j)
                red[stripe][h*256 + c0 + j] = acc[h][j];
    }
    __syncthreads();
    for (int i = tid; i < 2048; i += 256)
        red[0][i] = red[0][i] + red[1][i] + red[2][i] + red[3][i];
    __syncthreads();
    // out: 2 threads per output column
    {
        const int n = tid & 127, half = tid >> 7;
        float o = 0.0f;
        const int kbase = half * 1024;
        for (int k = 0; k < 1024; ++k)
            o = fmaf(red[0][kbase + k], wcc[(size_t)(kbase + k) * 128 + n], o);
        float* r2 = &sc[0][0];
        r2[half * 128 + n] = o;
    }
    __syncthreads();
    if (tid < 128)
        out[(size_t)b * 128 + tid] = relu_f(sc[0][tid] + sc[0][128 + tid] + bcc[tid]);
}

// ---------------------------------------------------------------------------
extern "C" void kernel_launch(void* const* d_in, const int* in_sizes, int n_in,
                              void* d_out, int out_size, void* d_ws, size_t ws_size,
                              hipStream_t stream)
{
    (void)in_sizes; (void)n_in; (void)out_size; (void)ws_size;
    const float* d1  = (const float*)d_in[0];
    const float* d2  = (const float*)d_in[1];
    const float* w1  = (const float*)d_in[2];
    const float* b1  = (const float*)d_in[3];
    const float* W   = (const float*)d_in[4];
    const float* P   = (const float*)d_in[5];
    const float* wv  = (const float*)d_in[6];
    const float* wcc = (const float*)d_in[7];
    const float* bcc = (const float*)d_in[8];
    float* out = (float*)d_out;

    char* p = (char*)d_ws;
    unsigned short* d3s  = (unsigned short*)p; p += (size_t)8 * SB * 64 * 2;       // 33.55 MB
    unsigned short* tv   = (unsigned short*)p; p += (size_t)SB * CC * 2;           // 16.78 MB
    unsigned short* w1ts = (unsigned short*)p; p += (size_t)16 * CC * 64 * 2;      // 512 KB
    unsigned short* wvts = (unsigned short*)p; p += (size_t)16 * CC * 64 * 2;      // 512 KB
    unsigned short* Wts  = (unsigned short*)p; p += (size_t)HH * 8 * CC * 64 * 2;  // 2 MB
    float* d4   = (float*)p;  p += (size_t)BB * CC * 4;
    float* e4   = (float*)p;  p += (size_t)HH * BB * CC * 4;
    float* atts = (float*)p;  p += (size_t)HH * BB * SS * 4;

    p_prep   <<<dim3(196),       256, 0, stream>>>(w1, wv, W, d1, b1,
                  w1ts, wvts, Wts, d4);
    k1_main  <<<dim3(544),       256, 0, stream>>>(d2, w1ts, wvts, b1, d4, W,
                  d3s, tv, e4);
    k3_atts  <<<dim3(2048),      256, 0, stream>>>(d3s, Wts, e4, P, atts);
    k456_out <<<dim3(BB),        256, 0, stream>>>(atts, tv, wcc, bcc, out);
}